// Round 13
// baseline (150.310 us; speedup 1.0000x reference)
//
#include <hip/hip_runtime.h>
#include <math.h>

#define NR 8192
#define N_OSC 28
#define TWO_PI_F 6.28318530717958647692f
#define PLANE 524288   // 8192 rows * 64 k, ushorts, per plane

typedef __attribute__((ext_vector_type(8))) short s16x8;
typedef __attribute__((ext_vector_type(16))) float f32x16;
typedef __attribute__((ext_vector_type(4))) float f32x4;
typedef __attribute__((ext_vector_type(4))) unsigned int u32x4;

__device__ __forceinline__ float modpos(float x) {
    float r = fmodf(x, TWO_PI_F);
    if (r < 0.0f) r += TWO_PI_F;
    return r;
}
__device__ __forceinline__ unsigned fmono(float f) {
    unsigned u = __float_as_uint(f);
    return (u & 0x80000000u) ? ~u : (u | 0x80000000u);
}
__device__ __forceinline__ unsigned short f2bf(float f) {  // RNE f32->bf16 bits
    unsigned u = __float_as_uint(f);
    return (unsigned short)((u + 0x7FFFu + ((u >> 16) & 1u)) >> 16);
}
__device__ __forceinline__ float bf2f(unsigned short h) {
    return __uint_as_float(((unsigned)h) << 16);
}

// Fragment-major table layout: element (row, k) ->
//   (row>>5)*2048 + (k>>4)*512 + ((k>>3)&1)*256 + (row&31)*8 + (k&7)
// so a wave's (group, ks) fragment load is 1KB contiguous: base + lane*8 ushorts.

// -------- phase encode + advance + bf16 hi/mid/lo planes (fragment-major) --------
__global__ __launch_bounds__(256, 1) void encode_kernel(
    const float* __restrict__ detA, const float* __restrict__ detB,
    const float* __restrict__ W1, const float* __restrict__ b1,
    const float* __restrict__ W2, const float* __restrict__ b2,
    const float* __restrict__ freq,
    unsigned short* __restrict__ tabA, unsigned short* __restrict__ tabB,
    float* __restrict__ normA, float* __restrict__ normB)
{
    __shared__ float sW1[4 * 64];
    __shared__ float sb1[64];
    __shared__ float sW2[64 * N_OSC];
    __shared__ float sb2[N_OSC];
    __shared__ float sDelta[N_OSC];

    int t = threadIdx.x;
    for (int i = t; i < 4 * 64; i += 256) sW1[i] = W1[i];
    for (int i = t; i < 64; i += 256) sb1[i] = b1[i];
    for (int i = t; i < 64 * N_OSC; i += 256) sW2[i] = W2[i];
    for (int i = t; i < N_OSC; i += 256) {
        sb2[i] = b2[i];
        sDelta[i] = (TWO_PI_F * freq[i]) * 0.01f;
    }
    __syncthreads();

    int gid = blockIdx.x * 256 + t;
    bool isA = gid < NR;
    int row = isA ? gid : gid - NR;
    const float* det = isA ? detA : detB;
    unsigned short* tab = isA ? tabA : tabB;
    float* nrm = isA ? normA : normB;

    float4 xv = *(const float4*)(det + (size_t)row * 4);
    float x0 = xv.x, x1 = xv.y, x2 = xv.z, x3 = xv.w;

    float h[64];
#pragma unroll
    for (int j = 0; j < 64; ++j) {
        float a = x0 * sW1[0 * 64 + j];
        a += x1 * sW1[1 * 64 + j];
        a += x2 * sW1[2 * 64 + j];
        a += x3 * sW1[3 * 64 + j];
        a += sb1[j];
        h[j] = fmaxf(a, 0.0f);
    }

    float raw[N_OSC];
#pragma unroll
    for (int o = 0; o < N_OSC; ++o) raw[o] = 0.0f;
#pragma unroll
    for (int j = 0; j < 64; ++j) {
        float hj = h[j];
#pragma unroll
        for (int o = 0; o < N_OSC; ++o) raw[o] += hj * sW2[j * N_OSC + o];
    }

    // packed bf16 planes: h2/m2/l2[i] holds k=2i (lo16) and k=2i+1 (hi16)
    unsigned h2[32], m2[32], l2[32];
#pragma unroll
    for (int i = 0; i < 32; ++i) { h2[i] = 0u; m2[i] = 0u; l2[i] = 0u; }

    float csum = 0.0f;
#pragma unroll
    for (int o = 0; o < N_OSC; ++o) {
        float p = raw[o] + sb2[o];
        p = modpos(p);
        if (isA) {
            float d = sDelta[o];
#pragma unroll
            for (int s = 0; s < 5; ++s) { p = modpos(p + d); }
        }
        float sn, cs;
        sincosf(p, &sn, &cs);
        csum += cs * cs + sn * sn;
        {   // k = o (cos)
            unsigned short v0 = f2bf(cs); float r1 = cs - bf2f(v0);
            unsigned short v1 = f2bf(r1); float r2 = r1 - bf2f(v1);
            unsigned short v2 = f2bf(r2);
            const int k = o, i = k >> 1, sh = (k & 1) * 16;
            h2[i] |= ((unsigned)v0) << sh;
            m2[i] |= ((unsigned)v1) << sh;
            l2[i] |= ((unsigned)v2) << sh;
        }
        {   // k = 28 + o (sin)
            unsigned short v0 = f2bf(sn); float r1 = sn - bf2f(v0);
            unsigned short v1 = f2bf(r1); float r2 = r1 - bf2f(v1);
            unsigned short v2 = f2bf(r2);
            const int k = 28 + o, i = k >> 1, sh = (k & 1) * 16;
            h2[i] |= ((unsigned)v0) << sh;
            m2[i] |= ((unsigned)v1) << sh;
            l2[i] |= ((unsigned)v2) << sh;
        }
    }

    // store 8 chunks of 8 k's (16B) per plane; coalesced across rows
    size_t gbase = (size_t)(row >> 5) * 2048 + (size_t)(row & 31) * 8;
#pragma unroll
    for (int c = 0; c < 8; ++c) {
        size_t off = gbase + (size_t)(c >> 1) * 512 + (size_t)(c & 1) * 256;
        u32x4 vh, vm, vl;
#pragma unroll
        for (int e = 0; e < 4; ++e) {
            vh[e] = h2[c * 4 + e]; vm[e] = m2[c * 4 + e]; vl[e] = l2[c * 4 + e];
        }
        *(u32x4*)(tab + off) = vh;
        *(u32x4*)(tab + PLANE + off) = vm;
        *(u32x4*)(tab + 2 * PLANE + off) = vl;
    }
    nrm[row] = 1.0f / (sqrtf(csum) + 1e-6f);    // reciprocal norm
}

#define MFMA(a, b, c) __builtin_amdgcn_mfma_f32_32x32x16_bf16((a), (b), (c), 0, 0, 0)

// -------- sim: direct-from-L2 fragment loads, no staging, no barriers --------
__global__ __launch_bounds__(256) void sim_kernel(
    const unsigned short* __restrict__ tabA, const unsigned short* __restrict__ tabB,
    const float* __restrict__ normA, const float* __restrict__ normB,
    float* __restrict__ simOut, unsigned long long* __restrict__ rowMax)
{
    __shared__ __align__(16) float scrAll[4][64 * 68];   // 69632 B, wave-private

    int bid = blockIdx.x;
    int swz = (bid & 7) * 512 + (bid >> 3);
    int bx = swz & 63, by = swz >> 6;
    int r0 = by * 128, c0 = bx * 128;

    int t = threadIdx.x, w = t >> 6, l = t & 63;
    int wr = w >> 1, wc = w & 1;
    int lrow = l & 31;
    int gA = (r0 + wr * 64) >> 5;      // A groups gA, gA+1
    int gB = (c0 + wc * 64) >> 5;      // B groups gB, gB+1
    size_t l8 = (size_t)l * 8;

#define LD(tab, pl, g, ks) \
    (*(const s16x8*)((tab) + (size_t)(pl) * PLANE + (size_t)(g) * 2048 + (size_t)(ks) * 512 + l8))

    f32x16 acc00, acc01, acc10, acc11;
#pragma unroll
    for (int r = 0; r < 16; ++r) { acc00[r] = 0.f; acc01[r] = 0.f; acc10[r] = 0.f; acc11[r] = 0.f; }

#pragma unroll
    for (int ks = 0; ks < 4; ++ks) {
        s16x8 ah0 = LD(tabA, 0, gA, ks),     ah1 = LD(tabA, 0, gA + 1, ks);
        s16x8 bh0 = LD(tabB, 0, gB, ks),     bh1 = LD(tabB, 0, gB + 1, ks);
        s16x8 am0 = LD(tabA, 1, gA, ks),     am1 = LD(tabA, 1, gA + 1, ks);
        s16x8 bm0 = LD(tabB, 1, gB, ks),     bm1 = LD(tabB, 1, gB + 1, ks);
        s16x8 al0 = LD(tabA, 2, gA, ks),     al1 = LD(tabA, 2, gA + 1, ks);
        s16x8 bl0 = LD(tabB, 2, gB, ks),     bl1 = LD(tabB, 2, gB + 1, ks);

        acc00 = MFMA(ah0, bh0, acc00); acc01 = MFMA(ah0, bh1, acc01);   // hh
        acc10 = MFMA(ah1, bh0, acc10); acc11 = MFMA(ah1, bh1, acc11);
        acc00 = MFMA(ah0, bm0, acc00); acc01 = MFMA(ah0, bm1, acc01);   // hm
        acc10 = MFMA(ah1, bm0, acc10); acc11 = MFMA(ah1, bm1, acc11);
        acc00 = MFMA(am0, bh0, acc00); acc01 = MFMA(am0, bh1, acc01);   // mh
        acc10 = MFMA(am1, bh0, acc10); acc11 = MFMA(am1, bh1, acc11);
        acc00 = MFMA(am0, bm0, acc00); acc01 = MFMA(am0, bm1, acc01);   // mm
        acc10 = MFMA(am1, bm0, acc10); acc11 = MFMA(am1, bm1, acc11);
        acc00 = MFMA(ah0, bl0, acc00); acc01 = MFMA(ah0, bl1, acc01);   // hl
        acc10 = MFMA(ah1, bl0, acc10); acc11 = MFMA(ah1, bl1, acc11);
        acc00 = MFMA(al0, bh0, acc00); acc01 = MFMA(al0, bh1, acc01);   // lh
        acc10 = MFMA(al1, bh0, acc10); acc11 = MFMA(al1, bh1, acc11);
    }
#undef LD

    float icn0 = normB[c0 + wc * 64 + lrow];        // reciprocal norms
    float icn1 = normB[c0 + wc * 64 + 32 + lrow];

    float* scr = scrAll[w];                          // 64 rows x pitch 68 floats

#pragma unroll
    for (int r = 0; r < 16; ++r) {
        int rd0 = (r & 3) + 8 * (r >> 2) + 4 * (l >> 5);
        float irn0 = normA[r0 + wr * 64 + rd0];
        scr[rd0 * 68 + lrow]      = acc00[r] * (irn0 * icn0);
        scr[rd0 * 68 + 32 + lrow] = acc01[r] * (irn0 * icn1);
        int rd1 = rd0 + 32;
        float irn1 = normA[r0 + wr * 64 + rd1];
        scr[rd1 * 68 + lrow]      = acc10[r] * (irn1 * icn0);
        scr[rd1 * 68 + 32 + lrow] = acc11[r] * (irn1 * icn1);
    }
    // wave-private scratch: no barrier needed

    // coalesced NT stores: 16 insts x 1KB
#pragma unroll
    for (int s = 0; s < 16; ++s) {
        int lr = 4 * s + (l >> 4);
        f32x4 v = *(const f32x4*)&scr[lr * 68 + (l & 15) * 4];
        int grow = r0 + wr * 64 + lr;
        __builtin_nontemporal_store(v,
            (f32x4*)&simOut[(size_t)grow * NR + c0 + wc * 64 + (l & 15) * 4]);
    }

    // per-lane row max: lane l owns row l of the wave tile
    {
        const float* rp = &scr[l * 68];
        float mv = -2.0f; int mc = 0;
#pragma unroll
        for (int c4 = 0; c4 < 16; ++c4) {
            f32x4 v = *(const f32x4*)&rp[c4 * 4];
#pragma unroll
            for (int e = 0; e < 4; ++e) {
                bool g = v[e] > mv;
                mv = g ? v[e] : mv;
                mc = g ? c4 * 4 + e : mc;
            }
        }
        int grow = r0 + wr * 64 + l;
        unsigned gcol = (unsigned)(c0 + wc * 64 + mc);
        unsigned long long key = ((unsigned long long)fmono(mv) << 32)
                               | (unsigned long long)(0xFFFFFFFFu - gcol);
        atomicMax(&rowMax[grow], key);
    }
}

// -------- per-row: init matches, claim column --------
__global__ __launch_bounds__(256) void rowwin_kernel(
    const unsigned long long* __restrict__ rowMax,
    unsigned long long* __restrict__ colWin,
    float* __restrict__ outMatches)
{
    int r = blockIdx.x * 256 + threadIdx.x;
    if (r >= NR) return;
    outMatches[r] = -1.0f;
    unsigned long long key = rowMax[r];
    unsigned m = (unsigned)(key >> 32);
    unsigned bits = (m & 0x80000000u) ? (m ^ 0x80000000u) : ~m;
    float ms = __uint_as_float(bits);
    unsigned col = 0xFFFFFFFFu - (unsigned)key;
    if (ms > 0.3f) {
        unsigned long long ck = ((unsigned long long)m << 32)
                              | (unsigned long long)(0xFFFFFFFFu - (unsigned)r);
        atomicMax(&colWin[col], ck);
    }
}

// -------- per-column: winner takes the column --------
__global__ __launch_bounds__(256) void colfin_kernel(
    const unsigned long long* __restrict__ colWin,
    float* __restrict__ outMatches)
{
    int j = blockIdx.x * 256 + threadIdx.x;
    if (j >= NR) return;
    unsigned long long w = colWin[j];
    if (w != 0ull) {
        unsigned r = 0xFFFFFFFFu - (unsigned)w;
        outMatches[r] = (float)j;
    }
}

extern "C" void kernel_launch(void* const* d_in, const int* in_sizes, int n_in,
                              void* d_out, int out_size, void* d_ws, size_t ws_size,
                              hipStream_t stream) {
    const float* detA = (const float*)d_in[0];
    const float* detB = (const float*)d_in[1];
    const float* W1   = (const float*)d_in[2];
    const float* b1   = (const float*)d_in[3];
    const float* W2   = (const float*)d_in[4];
    const float* b2   = (const float*)d_in[5];
    const float* freq = (const float*)d_in[6];
    float* out = (float*)d_out;

    char* ws = (char*)d_ws;
    unsigned short* tabA = (unsigned short*)(ws);             // 3 planes x 1 MB
    unsigned short* tabB = (unsigned short*)(ws + 3145728);   // 3 planes x 1 MB
    float* normA = (float*)(ws + 6291456);
    float* normB = (float*)(ws + 6324224);
    unsigned long long* rowMax = (unsigned long long*)(ws + 6356992);
    unsigned long long* colWin = (unsigned long long*)(ws + 6422528);

    (void)hipMemsetAsync(rowMax, 0, NR * 8, stream);
    (void)hipMemsetAsync(colWin, 0, NR * 8, stream);

    encode_kernel<<<64, 256, 0, stream>>>(detA, detB, W1, b1, W2, b2, freq,
                                          tabA, tabB, normA, normB);
    sim_kernel<<<4096, 256, 0, stream>>>(tabA, tabB, normA, normB, out + NR, rowMax);
    rowwin_kernel<<<NR / 256, 256, 0, stream>>>(rowMax, colWin, out);
    colfin_kernel<<<NR / 256, 256, 0, stream>>>(colWin, out);
}

// Round 14
// 149.400 us; speedup vs baseline: 1.0061x; 1.0061x over previous
//
#include <hip/hip_runtime.h>
#include <math.h>

#define NR 8192
#define N_OSC 28
#define TWO_PI_F 6.28318530717958647692f
#define PLANE 524288   // 8192 rows * 64 k, ushorts, per plane

typedef __attribute__((ext_vector_type(8))) short s16x8;
typedef __attribute__((ext_vector_type(16))) float f32x16;
typedef __attribute__((ext_vector_type(4))) float f32x4;
typedef __attribute__((ext_vector_type(4))) unsigned int u32x4;

#define AS3(p) ((__attribute__((address_space(3))) void*)(p))
#define AS1C(p) ((const __attribute__((address_space(1))) void*)(p))

__device__ __forceinline__ float modpos(float x) {
    float r = fmodf(x, TWO_PI_F);
    if (r < 0.0f) r += TWO_PI_F;
    return r;
}
__device__ __forceinline__ unsigned fmono(float f) {
    unsigned u = __float_as_uint(f);
    return (u & 0x80000000u) ? ~u : (u | 0x80000000u);
}
__device__ __forceinline__ unsigned short f2bf(float f) {  // RNE f32->bf16 bits
    unsigned u = __float_as_uint(f);
    return (unsigned short)((u + 0x7FFFu + ((u >> 16) & 1u)) >> 16);
}
__device__ __forceinline__ float bf2f(unsigned short h) {
    return __uint_as_float(((unsigned)h) << 16);
}

// Fragment-major table layout: element (row, k) ->
//   (row>>5)*2048 + (k>>4)*512 + ((k>>3)&1)*256 + (row&31)*8 + (k&7)
// A wave's (group, ks) fragment is 1KB contiguous: base + lane*8 ushorts.

// -------- phase encode + advance + bf16 hi/mid/lo planes (fragment-major) --------
__global__ __launch_bounds__(256, 1) void encode_kernel(
    const float* __restrict__ detA, const float* __restrict__ detB,
    const float* __restrict__ W1, const float* __restrict__ b1,
    const float* __restrict__ W2, const float* __restrict__ b2,
    const float* __restrict__ freq,
    unsigned short* __restrict__ tabA, unsigned short* __restrict__ tabB,
    float* __restrict__ normA, float* __restrict__ normB)
{
    __shared__ float sW1[4 * 64];
    __shared__ float sb1[64];
    __shared__ float sW2[64 * N_OSC];
    __shared__ float sb2[N_OSC];
    __shared__ float sDelta[N_OSC];

    int t = threadIdx.x;
    for (int i = t; i < 4 * 64; i += 256) sW1[i] = W1[i];
    for (int i = t; i < 64; i += 256) sb1[i] = b1[i];
    for (int i = t; i < 64 * N_OSC; i += 256) sW2[i] = W2[i];
    for (int i = t; i < N_OSC; i += 256) {
        sb2[i] = b2[i];
        sDelta[i] = (TWO_PI_F * freq[i]) * 0.01f;
    }
    __syncthreads();

    int gid = blockIdx.x * 256 + t;
    bool isA = gid < NR;
    int row = isA ? gid : gid - NR;
    const float* det = isA ? detA : detB;
    unsigned short* tab = isA ? tabA : tabB;
    float* nrm = isA ? normA : normB;

    float4 xv = *(const float4*)(det + (size_t)row * 4);
    float x0 = xv.x, x1 = xv.y, x2 = xv.z, x3 = xv.w;

    float h[64];
#pragma unroll
    for (int j = 0; j < 64; ++j) {
        float a = x0 * sW1[0 * 64 + j];
        a += x1 * sW1[1 * 64 + j];
        a += x2 * sW1[2 * 64 + j];
        a += x3 * sW1[3 * 64 + j];
        a += sb1[j];
        h[j] = fmaxf(a, 0.0f);
    }

    float raw[N_OSC];
#pragma unroll
    for (int o = 0; o < N_OSC; ++o) raw[o] = 0.0f;
#pragma unroll
    for (int j = 0; j < 64; ++j) {
        float hj = h[j];
#pragma unroll
        for (int o = 0; o < N_OSC; ++o) raw[o] += hj * sW2[j * N_OSC + o];
    }

    unsigned h2[32], m2[32], l2[32];
#pragma unroll
    for (int i = 0; i < 32; ++i) { h2[i] = 0u; m2[i] = 0u; l2[i] = 0u; }

    float csum = 0.0f;
#pragma unroll
    for (int o = 0; o < N_OSC; ++o) {
        float p = raw[o] + sb2[o];
        p = modpos(p);
        if (isA) {
            float d = sDelta[o];
#pragma unroll
            for (int s = 0; s < 5; ++s) { p = modpos(p + d); }
        }
        float sn, cs;
        sincosf(p, &sn, &cs);
        csum += cs * cs + sn * sn;
        {   // k = o (cos)
            unsigned short v0 = f2bf(cs); float r1 = cs - bf2f(v0);
            unsigned short v1 = f2bf(r1); float r2 = r1 - bf2f(v1);
            unsigned short v2 = f2bf(r2);
            const int k = o, i = k >> 1, sh = (k & 1) * 16;
            h2[i] |= ((unsigned)v0) << sh;
            m2[i] |= ((unsigned)v1) << sh;
            l2[i] |= ((unsigned)v2) << sh;
        }
        {   // k = 28 + o (sin)
            unsigned short v0 = f2bf(sn); float r1 = sn - bf2f(v0);
            unsigned short v1 = f2bf(r1); float r2 = r1 - bf2f(v1);
            unsigned short v2 = f2bf(r2);
            const int k = 28 + o, i = k >> 1, sh = (k & 1) * 16;
            h2[i] |= ((unsigned)v0) << sh;
            m2[i] |= ((unsigned)v1) << sh;
            l2[i] |= ((unsigned)v2) << sh;
        }
    }

    size_t gbase = (size_t)(row >> 5) * 2048 + (size_t)(row & 31) * 8;
#pragma unroll
    for (int c = 0; c < 8; ++c) {
        size_t off = gbase + (size_t)(c >> 1) * 512 + (size_t)(c & 1) * 256;
        u32x4 vh, vm, vl;
#pragma unroll
        for (int e = 0; e < 4; ++e) {
            vh[e] = h2[c * 4 + e]; vm[e] = m2[c * 4 + e]; vl[e] = l2[c * 4 + e];
        }
        *(u32x4*)(tab + off) = vh;
        *(u32x4*)(tab + PLANE + off) = vm;
        *(u32x4*)(tab + 2 * PLANE + off) = vl;
    }
    nrm[row] = 1.0f / (sqrtf(csum) + 1e-6f);    // reciprocal norm
}

#define MFMA(a, b, c) __builtin_amdgcn_mfma_f32_32x32x16_bf16((a), (b), (c), 0, 0, 0)

// -------- sim: B once->regs (L2), A via glds->LDS, 1-barrier main loop --------
__global__ __launch_bounds__(256, 1) void sim_kernel(
    const unsigned short* __restrict__ tabA, const unsigned short* __restrict__ tabB,
    const float* __restrict__ normA, const float* __restrict__ normB,
    float* __restrict__ simOut, unsigned long long* __restrict__ rowMax)
{
    __shared__ __align__(16) unsigned char smem[69632];  // A staging (48KB) then scratch
    unsigned short* Ash = (unsigned short*)smem;

    int bid = blockIdx.x;
    int swz = (bid & 7) * 512 + (bid >> 3);
    int bx = swz & 63, by = swz >> 6;
    int r0 = by * 128, c0 = bx * 128;

    int t = threadIdx.x, w = t >> 6, l = t & 63;
    int wr = w >> 1, wc = w & 1;
    int lrow = l & 31;
    int gB = (c0 + wc * 64) >> 5;      // B groups gB, gB+1
    int gr0 = r0 >> 5;                 // A group base for this block
    size_t l8 = (size_t)l * 8;

#define GLD(tab, pl, g, ks) \
    (*(const s16x8*)((tab) + (size_t)(pl) * PLANE + (size_t)(g) * 2048 + (size_t)(ks) * 512 + l8))

    // ---- B fragments: load once from L2 into 96 VGPRs ----
    s16x8 bh0[4], bh1[4], bm0[4], bm1[4], bl0[4], bl1[4];
#pragma unroll
    for (int ks = 0; ks < 4; ++ks) {
        bh0[ks] = GLD(tabB, 0, gB, ks);  bh1[ks] = GLD(tabB, 0, gB + 1, ks);
        bm0[ks] = GLD(tabB, 1, gB, ks);  bm1[ks] = GLD(tabB, 1, gB + 1, ks);
        bl0[ks] = GLD(tabB, 2, gB, ks);  bl1[ks] = GLD(tabB, 2, gB + 1, ks);
    }
#undef GLD

    // ---- A: stage all 3 planes (48 units x 1KB) via global_load_lds ----
#pragma unroll
    for (int i = 0; i < 12; ++i) {
        int unit = w * 12 + i;
        int p = unit >> 4, rem = unit & 15;          // plane, then group/ks
        int g = rem >> 2, ks = rem & 3;
        const unsigned short* src = tabA + (size_t)p * PLANE
            + (size_t)(gr0 + g) * 2048 + (size_t)ks * 512 + l8;
        __builtin_amdgcn_global_load_lds(AS1C(src), AS3(Ash + unit * 512), 16, 0, 0);
    }
    __builtin_amdgcn_sched_barrier(0);
    __syncthreads();

    f32x16 acc00, acc01, acc10, acc11;
#pragma unroll
    for (int r = 0; r < 16; ++r) { acc00[r] = 0.f; acc01[r] = 0.f; acc10[r] = 0.f; acc11[r] = 0.f; }

    // LDS A fragment: plane p, local group (2*wr + gg), ks ->
    //   byte offset = ((p*4 + 2*wr + gg)*4 + ks)*1024 + l*16
    const char* Ab = (const char*)Ash + (size_t)wr * 8192 + (size_t)l * 16;
#define LDA(p, gg, ks) (*(const s16x8*)(Ab + ((p) * 16384 + (gg) * 4096 + (ks) * 1024)))

#pragma unroll
    for (int ks = 0; ks < 4; ++ks) {
        s16x8 ah0 = LDA(0, 0, ks), ah1 = LDA(0, 1, ks);
        s16x8 am0 = LDA(1, 0, ks), am1 = LDA(1, 1, ks);
        s16x8 al0 = LDA(2, 0, ks), al1 = LDA(2, 1, ks);

        acc00 = MFMA(ah0, bh0[ks], acc00); acc01 = MFMA(ah0, bh1[ks], acc01);   // hh
        acc10 = MFMA(ah1, bh0[ks], acc10); acc11 = MFMA(ah1, bh1[ks], acc11);
        acc00 = MFMA(ah0, bm0[ks], acc00); acc01 = MFMA(ah0, bm1[ks], acc01);   // hm
        acc10 = MFMA(ah1, bm0[ks], acc10); acc11 = MFMA(ah1, bm1[ks], acc11);
        acc00 = MFMA(am0, bh0[ks], acc00); acc01 = MFMA(am0, bh1[ks], acc01);   // mh
        acc10 = MFMA(am1, bh0[ks], acc10); acc11 = MFMA(am1, bh1[ks], acc11);
        acc00 = MFMA(am0, bm0[ks], acc00); acc01 = MFMA(am0, bm1[ks], acc01);   // mm
        acc10 = MFMA(am1, bm0[ks], acc10); acc11 = MFMA(am1, bm1[ks], acc11);
        acc00 = MFMA(ah0, bl0[ks], acc00); acc01 = MFMA(ah0, bl1[ks], acc01);   // hl
        acc10 = MFMA(ah1, bl0[ks], acc10); acc11 = MFMA(ah1, bl1[ks], acc11);
        acc00 = MFMA(al0, bh0[ks], acc00); acc01 = MFMA(al0, bh1[ks], acc01);   // lh
        acc10 = MFMA(al1, bh0[ks], acc10); acc11 = MFMA(al1, bh1[ks], acc11);
    }
#undef LDA

    float icn0 = normB[c0 + wc * 64 + lrow];        // reciprocal norms
    float icn1 = normB[c0 + wc * 64 + 32 + lrow];

    __syncthreads();                                 // all A reads done; reuse LDS
    float* scr = (float*)(smem + w * 17408);         // 64 rows x pitch 68 floats

#pragma unroll
    for (int r = 0; r < 16; ++r) {
        int rd0 = (r & 3) + 8 * (r >> 2) + 4 * (l >> 5);
        float irn0 = normA[r0 + wr * 64 + rd0];
        scr[rd0 * 68 + lrow]      = acc00[r] * (irn0 * icn0);
        scr[rd0 * 68 + 32 + lrow] = acc01[r] * (irn0 * icn1);
        int rd1 = rd0 + 32;
        float irn1 = normA[r0 + wr * 64 + rd1];
        scr[rd1 * 68 + lrow]      = acc10[r] * (irn1 * icn0);
        scr[rd1 * 68 + 32 + lrow] = acc11[r] * (irn1 * icn1);
    }
    // wave-private scratch: no barrier needed between write and read

    // coalesced NT stores: 16 insts x 1KB
#pragma unroll
    for (int s = 0; s < 16; ++s) {
        int lr = 4 * s + (l >> 4);
        f32x4 v = *(const f32x4*)&scr[lr * 68 + (l & 15) * 4];
        int grow = r0 + wr * 64 + lr;
        __builtin_nontemporal_store(v,
            (f32x4*)&simOut[(size_t)grow * NR + c0 + wc * 64 + (l & 15) * 4]);
    }

    // per-lane row max: lane l owns row l of the wave tile
    {
        const float* rp = &scr[l * 68];
        float mv = -2.0f; int mc = 0;
#pragma unroll
        for (int c4 = 0; c4 < 16; ++c4) {
            f32x4 v = *(const f32x4*)&rp[c4 * 4];
#pragma unroll
            for (int e = 0; e < 4; ++e) {
                bool g = v[e] > mv;
                mv = g ? v[e] : mv;
                mc = g ? c4 * 4 + e : mc;
            }
        }
        int grow = r0 + wr * 64 + l;
        unsigned gcol = (unsigned)(c0 + wc * 64 + mc);
        unsigned long long key = ((unsigned long long)fmono(mv) << 32)
                               | (unsigned long long)(0xFFFFFFFFu - gcol);
        atomicMax(&rowMax[grow], key);
    }
}

// -------- per-row: init matches, claim column --------
__global__ __launch_bounds__(256) void rowwin_kernel(
    const unsigned long long* __restrict__ rowMax,
    unsigned long long* __restrict__ colWin,
    float* __restrict__ outMatches)
{
    int r = blockIdx.x * 256 + threadIdx.x;
    if (r >= NR) return;
    outMatches[r] = -1.0f;
    unsigned long long key = rowMax[r];
    unsigned m = (unsigned)(key >> 32);
    unsigned bits = (m & 0x80000000u) ? (m ^ 0x80000000u) : ~m;
    float ms = __uint_as_float(bits);
    unsigned col = 0xFFFFFFFFu - (unsigned)key;
    if (ms > 0.3f) {
        unsigned long long ck = ((unsigned long long)m << 32)
                              | (unsigned long long)(0xFFFFFFFFu - (unsigned)r);
        atomicMax(&colWin[col], ck);
    }
}

// -------- per-column: winner takes the column --------
__global__ __launch_bounds__(256) void colfin_kernel(
    const unsigned long long* __restrict__ colWin,
    float* __restrict__ outMatches)
{
    int j = blockIdx.x * 256 + threadIdx.x;
    if (j >= NR) return;
    unsigned long long w = colWin[j];
    if (w != 0ull) {
        unsigned r = 0xFFFFFFFFu - (unsigned)w;
        outMatches[r] = (float)j;
    }
}

extern "C" void kernel_launch(void* const* d_in, const int* in_sizes, int n_in,
                              void* d_out, int out_size, void* d_ws, size_t ws_size,
                              hipStream_t stream) {
    const float* detA = (const float*)d_in[0];
    const float* detB = (const float*)d_in[1];
    const float* W1   = (const float*)d_in[2];
    const float* b1   = (const float*)d_in[3];
    const float* W2   = (const float*)d_in[4];
    const float* b2   = (const float*)d_in[5];
    const float* freq = (const float*)d_in[6];
    float* out = (float*)d_out;

    char* ws = (char*)d_ws;
    unsigned short* tabA = (unsigned short*)(ws);             // 3 planes x 1 MB
    unsigned short* tabB = (unsigned short*)(ws + 3145728);   // 3 planes x 1 MB
    float* normA = (float*)(ws + 6291456);
    float* normB = (float*)(ws + 6324224);
    unsigned long long* rowMax = (unsigned long long*)(ws + 6356992);
    unsigned long long* colWin = (unsigned long long*)(ws + 6422528);

    (void)hipMemsetAsync(rowMax, 0, NR * 8, stream);
    (void)hipMemsetAsync(colWin, 0, NR * 8, stream);

    encode_kernel<<<64, 256, 0, stream>>>(detA, detB, W1, b1, W2, b2, freq,
                                          tabA, tabB, normA, normB);
    sim_kernel<<<4096, 256, 0, stream>>>(tabA, tabB, normA, normB, out + NR, rowMax);
    rowwin_kernel<<<NR / 256, 256, 0, stream>>>(rowMax, colWin, out);
    colfin_kernel<<<NR / 256, 256, 0, stream>>>(colWin, out);
}

// Round 15
// 142.068 us; speedup vs baseline: 1.0580x; 1.0516x over previous
//
#include <hip/hip_runtime.h>
#include <math.h>

#define NR 8192
#define N_OSC 28
#define TWO_PI_F 6.28318530717958647692f
#define PLANE 524288   // 8192 rows * 64 k, ushorts, per plane

typedef __attribute__((ext_vector_type(8))) short s16x8;
typedef __attribute__((ext_vector_type(16))) float f32x16;
typedef __attribute__((ext_vector_type(4))) float f32x4;
typedef __attribute__((ext_vector_type(4))) unsigned int u32x4;

#define AS3(p) ((__attribute__((address_space(3))) void*)(p))
#define AS1C(p) ((const __attribute__((address_space(1))) void*)(p))

__device__ __forceinline__ float modpos(float x) {
    float r = fmodf(x, TWO_PI_F);
    if (r < 0.0f) r += TWO_PI_F;
    return r;
}
__device__ __forceinline__ unsigned fmono(float f) {
    unsigned u = __float_as_uint(f);
    return (u & 0x80000000u) ? ~u : (u | 0x80000000u);
}
__device__ __forceinline__ unsigned short f2bf(float f) {  // RNE f32->bf16 bits
    unsigned u = __float_as_uint(f);
    return (unsigned short)((u + 0x7FFFu + ((u >> 16) & 1u)) >> 16);
}
__device__ __forceinline__ float bf2f(unsigned short h) {
    return __uint_as_float(((unsigned)h) << 16);
}

// Fragment-major table layout: element (row, k) ->
//   (row>>5)*2048 + (k>>4)*512 + ((k>>3)&1)*256 + (row&31)*8 + (k&7)
// A wave's (group, ks) fragment is 1KB contiguous: base + lane*8 ushorts.
// Values are PRE-SCALED by 1/norm so MFMA output is the final sim value.

// -------- phase encode + advance + norm-scaled bf16 hi/mid/lo planes --------
__global__ __launch_bounds__(256, 1) void encode_kernel(
    const float* __restrict__ detA, const float* __restrict__ detB,
    const float* __restrict__ W1, const float* __restrict__ b1,
    const float* __restrict__ W2, const float* __restrict__ b2,
    const float* __restrict__ freq,
    unsigned short* __restrict__ tabA, unsigned short* __restrict__ tabB)
{
    __shared__ float sW1[4 * 64];
    __shared__ float sb1[64];
    __shared__ float sW2[64 * N_OSC];
    __shared__ float sb2[N_OSC];
    __shared__ float sDelta[N_OSC];

    int t = threadIdx.x;
    for (int i = t; i < 4 * 64; i += 256) sW1[i] = W1[i];
    for (int i = t; i < 64; i += 256) sb1[i] = b1[i];
    for (int i = t; i < 64 * N_OSC; i += 256) sW2[i] = W2[i];
    for (int i = t; i < N_OSC; i += 256) {
        sb2[i] = b2[i];
        sDelta[i] = (TWO_PI_F * freq[i]) * 0.01f;
    }
    __syncthreads();

    int gid = blockIdx.x * 256 + t;
    bool isA = gid < NR;
    int row = isA ? gid : gid - NR;
    const float* det = isA ? detA : detB;
    unsigned short* tab = isA ? tabA : tabB;

    float4 xv = *(const float4*)(det + (size_t)row * 4);
    float x0 = xv.x, x1 = xv.y, x2 = xv.z, x3 = xv.w;

    float h[64];
#pragma unroll
    for (int j = 0; j < 64; ++j) {
        float a = x0 * sW1[0 * 64 + j];
        a += x1 * sW1[1 * 64 + j];
        a += x2 * sW1[2 * 64 + j];
        a += x3 * sW1[3 * 64 + j];
        a += sb1[j];
        h[j] = fmaxf(a, 0.0f);
    }

    float raw[N_OSC];
#pragma unroll
    for (int o = 0; o < N_OSC; ++o) raw[o] = 0.0f;
#pragma unroll
    for (int j = 0; j < 64; ++j) {
        float hj = h[j];
#pragma unroll
        for (int o = 0; o < N_OSC; ++o) raw[o] += hj * sW2[j * N_OSC + o];
    }

    float cv[N_OSC], sv[N_OSC];
    float csum = 0.0f;
#pragma unroll
    for (int o = 0; o < N_OSC; ++o) {
        float p = raw[o] + sb2[o];
        p = modpos(p);
        if (isA) {
            float d = sDelta[o];
#pragma unroll
            for (int s = 0; s < 5; ++s) { p = modpos(p + d); }
        }
        float sn, cs;
        sincosf(p, &sn, &cs);
        cv[o] = cs; sv[o] = sn;
        csum += cs * cs + sn * sn;
    }
    float irn = 1.0f / (sqrtf(csum) + 1e-6f);

    unsigned h2[32], m2[32], l2[32];
#pragma unroll
    for (int i = 0; i < 32; ++i) { h2[i] = 0u; m2[i] = 0u; l2[i] = 0u; }

#pragma unroll
    for (int o = 0; o < N_OSC; ++o) {
        {   // k = o (cos, scaled)
            float x = cv[o] * irn;
            unsigned short v0 = f2bf(x); float r1 = x - bf2f(v0);
            unsigned short v1 = f2bf(r1); float r2 = r1 - bf2f(v1);
            unsigned short v2 = f2bf(r2);
            const int k = o, i = k >> 1, sh = (k & 1) * 16;
            h2[i] |= ((unsigned)v0) << sh;
            m2[i] |= ((unsigned)v1) << sh;
            l2[i] |= ((unsigned)v2) << sh;
        }
        {   // k = 28 + o (sin, scaled)
            float x = sv[o] * irn;
            unsigned short v0 = f2bf(x); float r1 = x - bf2f(v0);
            unsigned short v1 = f2bf(r1); float r2 = r1 - bf2f(v1);
            unsigned short v2 = f2bf(r2);
            const int k = 28 + o, i = k >> 1, sh = (k & 1) * 16;
            h2[i] |= ((unsigned)v0) << sh;
            m2[i] |= ((unsigned)v1) << sh;
            l2[i] |= ((unsigned)v2) << sh;
        }
    }

    size_t gbase = (size_t)(row >> 5) * 2048 + (size_t)(row & 31) * 8;
#pragma unroll
    for (int c = 0; c < 8; ++c) {
        size_t off = gbase + (size_t)(c >> 1) * 512 + (size_t)(c & 1) * 256;
        u32x4 vh, vm, vl;
#pragma unroll
        for (int e = 0; e < 4; ++e) {
            vh[e] = h2[c * 4 + e]; vm[e] = m2[c * 4 + e]; vl[e] = l2[c * 4 + e];
        }
        *(u32x4*)(tab + off) = vh;
        *(u32x4*)(tab + PLANE + off) = vm;
        *(u32x4*)(tab + 2 * PLANE + off) = vl;
    }
}

#define MFMA(a, b, c) __builtin_amdgcn_mfma_f32_32x32x16_bf16((a), (b), (c), 0, 0, 0)

// -------- sim: 64x128 tiles, swapped-operand MFMA (lane holds sim-rows),
//          B once->regs, A via glds->LDS, in-register row-max --------
__global__ __launch_bounds__(128, 1) void sim_kernel(
    const unsigned short* __restrict__ tabA, const unsigned short* __restrict__ tabB,
    float* __restrict__ simOut, unsigned long long* __restrict__ rowMax)
{
    __shared__ __align__(16) unsigned char smem[33280];  // A staging 24KB, then 2x16640 scratch
    unsigned short* Ash = (unsigned short*)smem;

    int bid = blockIdx.x;
    int swz = (bid & 7) * 1024 + (bid >> 3);   // 8192 blocks, bijective XCD swizzle
    int bx = swz & 63, by = swz >> 6;          // 64 col-tiles x 128 row-tiles
    int r0 = by * 64, c0 = bx * 128;

    int t = threadIdx.x, w = t >> 6, l = t & 63;
    int wc = w;                    // wave owns cols [c0+wc*64, +64)
    int l31 = l & 31, h5 = l >> 5;
    int gB = (c0 + wc * 64) >> 5;
    int gr0 = r0 >> 5;
    size_t l8 = (size_t)l * 8;

#define GLD(tab, pl, g, ks) \
    (*(const s16x8*)((tab) + (size_t)(pl) * PLANE + (size_t)(g) * 2048 + (size_t)(ks) * 512 + l8))

    // ---- B fragments: load once from L2 into 96 VGPRs ----
    s16x8 bh0[4], bh1[4], bm0[4], bm1[4], bl0[4], bl1[4];
#pragma unroll
    for (int ks = 0; ks < 4; ++ks) {
        bh0[ks] = GLD(tabB, 0, gB, ks);  bh1[ks] = GLD(tabB, 0, gB + 1, ks);
        bm0[ks] = GLD(tabB, 1, gB, ks);  bm1[ks] = GLD(tabB, 1, gB + 1, ks);
        bl0[ks] = GLD(tabB, 2, gB, ks);  bl1[ks] = GLD(tabB, 2, gB + 1, ks);
    }
#undef GLD

    // ---- A: stage 2 groups x 3 planes x 4 ks = 24 x 1KB via glds ----
#pragma unroll
    for (int i = 0; i < 12; ++i) {
        int unit = w * 12 + i;                 // unit = p*8 + g*4 + ks
        int p = unit >> 3, rem = unit & 7;
        int g = rem >> 2, ks = rem & 3;
        const unsigned short* src = tabA + (size_t)p * PLANE
            + (size_t)(gr0 + g) * 2048 + (size_t)ks * 512 + l8;
        __builtin_amdgcn_global_load_lds(AS1C(src), AS3(Ash + unit * 512), 16, 0, 0);
    }
    __builtin_amdgcn_sched_barrier(0);
    __syncthreads();

    f32x16 acc00, acc01, acc10, acc11;   // acc[ag][bg]
#pragma unroll
    for (int r = 0; r < 16; ++r) { acc00[r] = 0.f; acc01[r] = 0.f; acc10[r] = 0.f; acc11[r] = 0.f; }

    const char* Ab = (const char*)Ash + (size_t)l * 16;
#define LDA(p, g, ks) (*(const s16x8*)(Ab + (((p) * 8 + (g) * 4 + (ks)) * 1024)))

#pragma unroll
    for (int ks = 0; ks < 4; ++ks) {
        s16x8 ah0 = LDA(0, 0, ks), ah1 = LDA(0, 1, ks);
        s16x8 am0 = LDA(1, 0, ks), am1 = LDA(1, 1, ks);
        s16x8 al0 = LDA(2, 0, ks), al1 = LDA(2, 1, ks);

        // D = X*Y with X = B-frag, Y = A-frag  =>  D[col-pattern, lane=row] = sim^T tile
        acc00 = MFMA(bh0[ks], ah0, acc00); acc01 = MFMA(bh1[ks], ah0, acc01);   // hh
        acc10 = MFMA(bh0[ks], ah1, acc10); acc11 = MFMA(bh1[ks], ah1, acc11);
        acc00 = MFMA(bm0[ks], ah0, acc00); acc01 = MFMA(bm1[ks], ah0, acc01);   // h*m
        acc10 = MFMA(bm0[ks], ah1, acc10); acc11 = MFMA(bm1[ks], ah1, acc11);
        acc00 = MFMA(bh0[ks], am0, acc00); acc01 = MFMA(bh1[ks], am0, acc01);   // m*h
        acc10 = MFMA(bh0[ks], am1, acc10); acc11 = MFMA(bh1[ks], am1, acc11);
        acc00 = MFMA(bm0[ks], am0, acc00); acc01 = MFMA(bm1[ks], am0, acc01);   // mm
        acc10 = MFMA(bm0[ks], am1, acc10); acc11 = MFMA(bm1[ks], am1, acc11);
        acc00 = MFMA(bl0[ks], ah0, acc00); acc01 = MFMA(bl1[ks], ah0, acc01);   // h*l
        acc10 = MFMA(bl0[ks], ah1, acc10); acc11 = MFMA(bl1[ks], ah1, acc11);
        acc00 = MFMA(bh0[ks], al0, acc00); acc01 = MFMA(bh1[ks], al0, acc01);   // l*h
        acc10 = MFMA(bh0[ks], al1, acc10); acc11 = MFMA(bh1[ks], al1, acc11);
    }
#undef LDA

    // ---- in-register row max/argmax (rows are lane-local now) ----
    // lane holds rows {r0 + l31, r0 + 32 + l31}; cols = c0+wc*64 + bg*32 + (r&3)+8*(r>>2)+4*h5
    int cbase = c0 + wc * 64 + 4 * h5;
    unsigned long long key0 = 0ull, key1 = 0ull;
#pragma unroll
    for (int r = 0; r < 16; ++r) {
        int pa = (r & 3) + 8 * (r >> 2);
        unsigned col0 = (unsigned)(cbase + pa);
        unsigned col1 = (unsigned)(cbase + 32 + pa);
        unsigned long long k;
        k = ((unsigned long long)fmono(acc00[r]) << 32) | (unsigned long long)(0xFFFFFFFFu - col0);
        if (k > key0) key0 = k;
        k = ((unsigned long long)fmono(acc01[r]) << 32) | (unsigned long long)(0xFFFFFFFFu - col1);
        if (k > key0) key0 = k;
        k = ((unsigned long long)fmono(acc10[r]) << 32) | (unsigned long long)(0xFFFFFFFFu - col0);
        if (k > key1) key1 = k;
        k = ((unsigned long long)fmono(acc11[r]) << 32) | (unsigned long long)(0xFFFFFFFFu - col1);
        if (k > key1) key1 = k;
    }
    {   // merge lane l <-> l+32 (same rows, complementary col subsets)
        unsigned lo = (unsigned)key0, hi = (unsigned)(key0 >> 32);
        unsigned olo = __shfl_xor(lo, 32, 64), ohi = __shfl_xor(hi, 32, 64);
        unsigned long long o = ((unsigned long long)ohi << 32) | olo;
        if (o > key0) key0 = o;
        lo = (unsigned)key1; hi = (unsigned)(key1 >> 32);
        olo = __shfl_xor(lo, 32, 64); ohi = __shfl_xor(hi, 32, 64);
        o = ((unsigned long long)ohi << 32) | olo;
        if (o > key1) key1 = o;
    }
    if (l < 32) {
        atomicMax(&rowMax[r0 + l], key0);
        atomicMax(&rowMax[r0 + 32 + l], key1);
    }

    // ---- store via LDS transpose scratch (pitch 65, conflict-light) ----
    __syncthreads();                       // both waves done reading Ash
    float* scr = (float*)(smem + w * 16640);   // 64 rows x pitch 65 floats

#pragma unroll
    for (int r = 0; r < 16; ++r) {
        int pa = (r & 3) + 8 * (r >> 2) + 4 * h5;
        scr[l31 * 65 + pa]             = acc00[r];
        scr[l31 * 65 + 32 + pa]        = acc01[r];
        scr[(32 + l31) * 65 + pa]      = acc10[r];
        scr[(32 + l31) * 65 + 32 + pa] = acc11[r];
    }
    // wave-private scratch: no barrier needed

#pragma unroll
    for (int s = 0; s < 16; ++s) {
        int lr = 4 * s + (l >> 4);
        f32x4 v = *(const f32x4*)&scr[lr * 65 + (l & 15) * 4];
        __builtin_nontemporal_store(v,
            (f32x4*)&simOut[(size_t)(r0 + lr) * NR + c0 + wc * 64 + (l & 15) * 4]);
    }
}

// -------- per-row: init matches, claim column --------
__global__ __launch_bounds__(256) void rowwin_kernel(
    const unsigned long long* __restrict__ rowMax,
    unsigned long long* __restrict__ colWin,
    float* __restrict__ outMatches)
{
    int r = blockIdx.x * 256 + threadIdx.x;
    if (r >= NR) return;
    outMatches[r] = -1.0f;
    unsigned long long key = rowMax[r];
    unsigned m = (unsigned)(key >> 32);
    unsigned bits = (m & 0x80000000u) ? (m ^ 0x80000000u) : ~m;
    float ms = __uint_as_float(bits);
    unsigned col = 0xFFFFFFFFu - (unsigned)key;
    if (ms > 0.3f) {
        unsigned long long ck = ((unsigned long long)m << 32)
                              | (unsigned long long)(0xFFFFFFFFu - (unsigned)r);
        atomicMax(&colWin[col], ck);
    }
}

// -------- per-column: winner takes the column --------
__global__ __launch_bounds__(256) void colfin_kernel(
    const unsigned long long* __restrict__ colWin,
    float* __restrict__ outMatches)
{
    int j = blockIdx.x * 256 + threadIdx.x;
    if (j >= NR) return;
    unsigned long long w = colWin[j];
    if (w != 0ull) {
        unsigned r = 0xFFFFFFFFu - (unsigned)w;
        outMatches[r] = (float)j;
    }
}

extern "C" void kernel_launch(void* const* d_in, const int* in_sizes, int n_in,
                              void* d_out, int out_size, void* d_ws, size_t ws_size,
                              hipStream_t stream) {
    const float* detA = (const float*)d_in[0];
    const float* detB = (const float*)d_in[1];
    const float* W1   = (const float*)d_in[2];
    const float* b1   = (const float*)d_in[3];
    const float* W2   = (const float*)d_in[4];
    const float* b2   = (const float*)d_in[5];
    const float* freq = (const float*)d_in[6];
    float* out = (float*)d_out;

    char* ws = (char*)d_ws;
    unsigned short* tabA = (unsigned short*)(ws);             // 3 planes x 1 MB
    unsigned short* tabB = (unsigned short*)(ws + 3145728);   // 3 planes x 1 MB
    unsigned long long* rowMax = (unsigned long long*)(ws + 6291456); // 64 KB
    unsigned long long* colWin = (unsigned long long*)(ws + 6356992); // 64 KB

    (void)hipMemsetAsync(rowMax, 0, NR * 8, stream);
    (void)hipMemsetAsync(colWin, 0, NR * 8, stream);

    encode_kernel<<<64, 256, 0, stream>>>(detA, detB, W1, b1, W2, b2, freq,
                                          tabA, tabB);
    sim_kernel<<<8192, 128, 0, stream>>>(tabA, tabB, out + NR, rowMax);
    rowwin_kernel<<<NR / 256, 256, 0, stream>>>(rowMax, colWin, out);
    colfin_kernel<<<NR / 256, 256, 0, stream>>>(colWin, out);
}